// Round 17
// baseline (287.194 us; speedup 1.0000x reference)
//
#include <hip/hip_runtime.h>
#include <hip/hip_bf16.h>
#include <cstdint>
#include <cstddef>

#define NN 50000        // nodes
#define NE 400000       // edges (without self loops)
#define NG 128
#define INCH 768
#define CONDCH 768
#define HIDD 128
#define NHEAD 4
#define F1 (NHEAD * HIDD)   // 512
#define F2 HIDD             // 128
#define MPAD 50176          // 196 * 256
#define CAP 64              // per-node edge bucket capacity (deg ~ Poisson(8))

typedef unsigned short ushort_t;
typedef float f32x4 __attribute__((ext_vector_type(4)));
typedef __bf16 bf16x8 __attribute__((ext_vector_type(8)));

typedef const void __attribute__((address_space(1))) as1_void;
typedef void __attribute__((address_space(3))) as3_void;

__device__ __forceinline__ void gload_lds16(const void* g, void* l) {
    __builtin_amdgcn_global_load_lds((as1_void*)g, (as3_void*)l, 16, 0, 0);
}

__device__ __forceinline__ ushort_t f2bf(float f) {
    uint32_t u = __float_as_uint(f);
    uint32_t r = (u + 0x7fffu + ((u >> 16) & 1u)) >> 16;
    return (ushort_t)r;
}
__device__ __forceinline__ uint32_t pack2(float a, float b) {
    return (uint32_t)f2bf(a) | ((uint32_t)f2bf(b) << 16);
}
__device__ __forceinline__ float bf_lo(uint32_t u) { return __uint_as_float(u << 16); }
__device__ __forceinline__ float bf_hi(uint32_t u) { return __uint_as_float(u & 0xffff0000u); }

// ---------------- k_prep: cond->bf16, weight transposes, bucket seed ------------
#define R1 (F1 * INCH)
#define R2 (R1 + F1 * CONDCH)
#define R3 (R2 + F2 * F1)
#define CND4 (NG * CONDCH / 4)
__global__ __launch_bounds__(256) void k_prep(
    const float* __restrict__ W1, const float* __restrict__ W2, const float* __restrict__ cond,
    ushort_t* __restrict__ W1aT, ushort_t* __restrict__ W1cT, ushort_t* __restrict__ W2T,
    ushort_t* __restrict__ condb, int* __restrict__ cursor, int* __restrict__ csr_src)
{
    int idx = blockIdx.x * blockDim.x + threadIdx.x;
    if (idx < NN) {
        cursor[idx] = 1;                       // self-loop pre-seeded
        csr_src[(size_t)idx * CAP] = idx;
    }
    if (idx < CND4) {
        float4 v = *(const float4*)(cond + (size_t)idx * 4);
        ushort4 o;
        o.x = f2bf(v.x); o.y = f2bf(v.y); o.z = f2bf(v.z); o.w = f2bf(v.w);
        *(ushort4*)(condb + (size_t)idx * 4) = o;
    }
    if (idx >= R3) return;
    if (idx < R1) {
        int n = idx / INCH, k = idx % INCH;
        W1aT[idx] = f2bf(W1[(size_t)k * F1 + n]);
    } else if (idx < R2) {
        int j = idx - R1;
        int n = j / CONDCH, k = j % CONDCH;
        W1cT[j] = f2bf(W1[(size_t)(INCH + k) * F1 + n]);
    } else {
        int j = idx - R2;
        int n = j / F1, k = j % F1;
        W2T[j] = f2bf(W2[(size_t)k * F2 + n]);
    }
}

// ---------------- edge scatter into buckets -----------------------
__global__ __launch_bounds__(256) void k_scat(const int* __restrict__ ei,
                                              int* __restrict__ cursor,
                                              int* __restrict__ csr_src) {
    int e = blockIdx.x * blockDim.x + threadIdx.x;
    if (e >= NE) return;
    int src = ei[e];
    int dst = ei[NE + e];
    int pos = atomicAdd(&cursor[dst], 1);
    csr_src[(size_t)dst * CAP + pos] = src;
}

// ---------------- x -> bf16: 32 elems/thread, 8 independent loads in flight -----
__global__ __launch_bounds__(256) void k_cvt32(const float* __restrict__ in,
                                               ushort_t* __restrict__ out, long n32) {
    long i = (long)blockIdx.x * blockDim.x + threadIdx.x;
    if (i >= n32) return;
    const float4* s = (const float4*)(in + i * 32);
    float4 v0 = s[0], v1 = s[1], v2 = s[2], v3 = s[3];
    float4 v4 = s[4], v5 = s[5], v6 = s[6], v7 = s[7];
    uint4 o0, o1, o2, o3;
    o0.x = pack2(v0.x, v0.y); o0.y = pack2(v0.z, v0.w);
    o0.z = pack2(v1.x, v1.y); o0.w = pack2(v1.z, v1.w);
    o1.x = pack2(v2.x, v2.y); o1.y = pack2(v2.z, v2.w);
    o1.z = pack2(v3.x, v3.y); o1.w = pack2(v3.z, v3.w);
    o2.x = pack2(v4.x, v4.y); o2.y = pack2(v4.z, v4.w);
    o2.z = pack2(v5.x, v5.y); o2.w = pack2(v5.z, v5.w);
    o3.x = pack2(v6.x, v6.y); o3.y = pack2(v6.z, v6.w);
    o3.z = pack2(v7.x, v7.y); o3.w = pack2(v7.z, v7.w);
    uint4* d = (uint4*)(out + i * 32);
    d[0] = o0; d[1] = o1; d[2] = o2; d[3] = o3;
}

// ---------------- bf16 MFMA GEMM: C[M,N] = A[M,K] @ BT[N,K]^T (+G[gidx[m],:]) ----
// TM x 128 tile, double-buffered LDS, 1 barrier per K-step:
//   { vmcnt(0); s_barrier; STAGE(t+1 -> buf^1); compute buf }
// 1-D grid, XCD-chunked bijective swizzle, n-fast ordering.
// FUSE_ATT: per-row dots with attS/attD -> aS/aD[m*attStride + by].
template <int TM, bool ADD_GATHER, bool OUT_BF16, bool FUSE_ATT>
__global__ __launch_bounds__(TM * 2) void k_mgemm(
    const ushort_t* __restrict__ A, const ushort_t* __restrict__ BT, void* __restrict__ Cv,
    int M, int N, int K, int nBN,
    const float* __restrict__ G, const int* __restrict__ gidx,
    const float* __restrict__ attS, const float* __restrict__ attD,
    float* __restrict__ aS, float* __restrict__ aD, int attStride)
{
    constexpr int SA = TM * 64;     // bytes per A buffer (TM rows x 64B)
    constexpr int SB = 8192;        // bytes per B buffer (128 rows x 64B)
    __shared__ __align__(16) char smem[2 * SA + 2 * SB];
    char* sA = smem;
    char* sB = smem + 2 * SA;

    const int nwg = gridDim.x;
    const int orig = blockIdx.x;
    const int q = nwg >> 3, r = nwg & 7;
    const int xcd = orig & 7, sid = orig >> 3;
    const int wg = (xcd < r ? xcd * (q + 1) : r * (q + 1) + (xcd - r) * q) + sid;
    const int bx = wg / nBN, by = wg % nBN;

    const int tid = threadIdx.x;
    const int lane = tid & 63;
    const int wave = tid >> 6;
    const int wr = wave >> 1, wc = wave & 1;
    const int m0 = bx * TM, n0 = by * 128;

    const int sr = tid >> 2;
    const int sc = (tid & 3) * 8;
    const ushort_t* gA = A + (size_t)(m0 + sr) * K + sc;
    const ushort_t* gB = BT + (size_t)(n0 + sr) * K + sc;
    const int ldsw = wave * 1024;

    const int a_off = (wr * 64 + (lane & 15)) * 64 + (lane >> 4) * 16;
    const int b_off = (wc * 64 + (lane & 15)) * 64 + (lane >> 4) * 16;

    auto STAGE = [&](int kt, int b) {
        char* dA = sA + b * SA + ldsw;
        gload_lds16(gA + kt, dA);
        gload_lds16(gA + (size_t)(TM / 2) * K + kt, dA + SA / 2);
        char* dB = sB + b * SB + ldsw;
        gload_lds16(gB + kt, dB);
        if (TM == 128)
            gload_lds16(gB + (size_t)64 * K + kt, dB + 4096);
    };

    f32x4 acc[4][4];
#pragma unroll
    for (int i = 0; i < 4; i++)
#pragma unroll
        for (int j = 0; j < 4; j++) acc[i][j] = 0.f;

    STAGE(0, 0);
    const int nt = K / 32;   // even for K in {768, 512}
    for (int t = 0; t < nt; t++) {
        const int cur = t & 1;
        asm volatile("s_waitcnt vmcnt(0)" ::: "memory");   // stage(t) landed
        __builtin_amdgcn_s_barrier();
        __builtin_amdgcn_sched_barrier(0);
        if (t + 1 < nt) STAGE((t + 1) * 32, cur ^ 1);      // in flight across compute
        bf16x8 af[4], bfr[4];
#pragma unroll
        for (int i = 0; i < 4; i++) af[i]  = *(const bf16x8*)(sA + cur * SA + a_off + i * 1024);
#pragma unroll
        for (int j = 0; j < 4; j++) bfr[j] = *(const bf16x8*)(sB + cur * SB + b_off + j * 1024);
#pragma unroll
        for (int i = 0; i < 4; i++)
#pragma unroll
            for (int j = 0; j < 4; j++)
                acc[i][j] = __builtin_amdgcn_mfma_f32_16x16x32_bf16(af[i], bfr[j], acc[i][j], 0, 0, 0);
    }
    // nt even => last compute read buffer 1; epilogue reuses buffer-0 region.

    float asv[4], adv[4];
    if (FUSE_ATT) {
#pragma unroll
        for (int j = 0; j < 4; j++) {
            int col = wc * 64 + j * 16 + (lane & 15);
            asv[j] = attS[by * 128 + col];
            adv[j] = attD[by * 128 + col];
        }
    }
    float* redS = (float*)smem;              // [2(wc)][TM]  (buffer-0 region)
    float* redD = (float*)smem + 2 * TM;

#pragma unroll
    for (int i = 0; i < 4; i++) {
        int mbase = m0 + wr * 64 + i * 16 + (lane >> 4) * 4;
#pragma unroll
        for (int rr = 0; rr < 4; rr++) {
            int m = mbase + rr;
            if (m >= M) continue;
            const float* grow = nullptr;
            if (ADD_GATHER) grow = G + (size_t)gidx[m] * N;
            float vs = 0.f, vd = 0.f;
#pragma unroll
            for (int j = 0; j < 4; j++) {
                int n = n0 + wc * 64 + j * 16 + (lane & 15);
                float v = acc[i][j][rr];
                if (ADD_GATHER) v += grow[n];
                if (OUT_BF16) ((ushort_t*)Cv)[(size_t)m * N + n] = f2bf(v);
                else          ((float*)Cv)[(size_t)m * N + n] = v;
                if (FUSE_ATT) { vs = fmaf(v, asv[j], vs); vd = fmaf(v, adv[j], vd); }
            }
            if (FUSE_ATT) {
#pragma unroll
                for (int o = 1; o < 16; o <<= 1) { vs += __shfl_xor(vs, o); vd += __shfl_xor(vd, o); }
                if ((lane & 15) == 0) {
                    int mloc = wr * 64 + i * 16 + (lane >> 4) * 4 + rr;
                    redS[wc * TM + mloc] = vs;
                    redD[wc * TM + mloc] = vd;
                }
            }
        }
    }
    if (FUSE_ATT) {
        __syncthreads();
        int sd = tid >= TM ? 1 : 0, mloc = tid & (TM - 1);
        int m = m0 + mloc;
        if (m < M) {
            const float* rb = sd ? redD : redS;
            float v = rb[mloc] + rb[TM + mloc];
            (sd ? aD : aS)[(size_t)m * attStride + by] = v;
        }
    }
}

// ---------------- aggregation layer1: one wave per node, in-kernel softmax ------
__global__ __launch_bounds__(256) void k_agg1(
    const ushort_t* __restrict__ h1, const float* __restrict__ a_src, const float* __restrict__ a_dst,
    const int* __restrict__ cnt, const int* __restrict__ csr_src,
    const float* __restrict__ b1, ushort_t* __restrict__ g1)
{
    const int n = blockIdx.x * 4 + (threadIdx.x >> 6);
    const int lane = threadIdx.x & 63;
    const int head = lane >> 4;
    const int beg = n * CAP;
    const int end = beg + cnt[n];
    const float4 ad = *(const float4*)(a_dst + (size_t)n * 4);

    // pass 1: per-head max (lanes parallel; deg<=CAP=64 -> single iteration)
    float mx[4] = {-1e30f, -1e30f, -1e30f, -1e30f};
    for (int p = beg + lane; p < end; p += 64) {
        int src = csr_src[p];
        float4 as = *(const float4*)(a_src + (size_t)src * 4);
        float v;
        v = as.x + ad.x; v = v >= 0.f ? v : 0.2f * v; mx[0] = fmaxf(mx[0], v);
        v = as.y + ad.y; v = v >= 0.f ? v : 0.2f * v; mx[1] = fmaxf(mx[1], v);
        v = as.z + ad.z; v = v >= 0.f ? v : 0.2f * v; mx[2] = fmaxf(mx[2], v);
        v = as.w + ad.w; v = v >= 0.f ? v : 0.2f * v; mx[3] = fmaxf(mx[3], v);
    }
#pragma unroll
    for (int o = 32; o; o >>= 1) {
        mx[0] = fmaxf(mx[0], __shfl_xor(mx[0], o));
        mx[1] = fmaxf(mx[1], __shfl_xor(mx[1], o));
        mx[2] = fmaxf(mx[2], __shfl_xor(mx[2], o));
        mx[3] = fmaxf(mx[3], __shfl_xor(mx[3], o));
    }
    const float m   = (head & 1) ? ((head & 2) ? mx[3] : mx[1]) : ((head & 2) ? mx[2] : mx[0]);
    const float adh = (head & 1) ? ((head & 2) ? ad.w : ad.y)   : ((head & 2) ? ad.z : ad.x);

    // pass 2: gather + exp + accumulate, 4-edge unroll, int4 index loads
    float ssum = 0.f;
    float a[8] = {0.f, 0.f, 0.f, 0.f, 0.f, 0.f, 0.f, 0.f};
    int p = beg;
#define LREL(l) ((l) >= 0.f ? (l) : 0.2f * (l))
#define ACC8(c, u) \
        a[0] = fmaf(c, bf_lo(u.x), a[0]); a[1] = fmaf(c, bf_hi(u.x), a[1]); \
        a[2] = fmaf(c, bf_lo(u.y), a[2]); a[3] = fmaf(c, bf_hi(u.y), a[3]); \
        a[4] = fmaf(c, bf_lo(u.z), a[4]); a[5] = fmaf(c, bf_hi(u.z), a[5]); \
        a[6] = fmaf(c, bf_lo(u.w), a[6]); a[7] = fmaf(c, bf_hi(u.w), a[7]);
    for (; p + 3 < end; p += 4) {
        int4 s4 = *(const int4*)(csr_src + p);   // bucket base 64-aligned -> p 4-aligned
        uint4 u0 = *(const uint4*)(h1 + (size_t)s4.x * F1 + lane * 8);
        uint4 u1 = *(const uint4*)(h1 + (size_t)s4.y * F1 + lane * 8);
        uint4 u2 = *(const uint4*)(h1 + (size_t)s4.z * F1 + lane * 8);
        uint4 u3 = *(const uint4*)(h1 + (size_t)s4.w * F1 + lane * 8);
        float c0 = expf(LREL(a_src[s4.x * 4 + head] + adh) - m);
        float c1 = expf(LREL(a_src[s4.y * 4 + head] + adh) - m);
        float c2 = expf(LREL(a_src[s4.z * 4 + head] + adh) - m);
        float c3 = expf(LREL(a_src[s4.w * 4 + head] + adh) - m);
        ssum += c0 + c1 + c2 + c3;
        ACC8(c0, u0) ACC8(c1, u1) ACC8(c2, u2) ACC8(c3, u3)
    }
    for (; p < end; p++) {
        int s0 = csr_src[p];
        uint4 u0 = *(const uint4*)(h1 + (size_t)s0 * F1 + lane * 8);
        float c0 = expf(LREL(a_src[s0 * 4 + head] + adh) - m);
        ssum += c0;
        ACC8(c0, u0)
    }
#undef ACC8
    const float inv = 1.0f / (ssum + 1e-16f);
    const int ch = lane * 8;
    float4 bA = *(const float4*)(b1 + ch);
    float4 bB = *(const float4*)(b1 + ch + 4);
    uint4 ov;
    ov.x = pack2(fmaxf(fmaf(a[0], inv, bA.x), 0.f), fmaxf(fmaf(a[1], inv, bA.y), 0.f));
    ov.y = pack2(fmaxf(fmaf(a[2], inv, bA.z), 0.f), fmaxf(fmaf(a[3], inv, bA.w), 0.f));
    ov.z = pack2(fmaxf(fmaf(a[4], inv, bB.x), 0.f), fmaxf(fmaf(a[5], inv, bB.y), 0.f));
    ov.w = pack2(fmaxf(fmaf(a[6], inv, bB.z), 0.f), fmaxf(fmaf(a[7], inv, bB.w), 0.f));
    *(uint4*)(g1 + (size_t)n * F1 + ch) = ov;
}

// ---------------- aggregation layer2 + final linear: one wave per node ------
__global__ __launch_bounds__(256) void k_agg2(
    const ushort_t* __restrict__ h2, const float* __restrict__ a_src, const float* __restrict__ a_dst,
    const int* __restrict__ cnt, const int* __restrict__ csr_src,
    const float* __restrict__ b2, const float* __restrict__ outW, const float* __restrict__ outb,
    float* __restrict__ out)
{
    const int n = blockIdx.x * 4 + (threadIdx.x >> 6);
    const int lane = threadIdx.x & 63;
    const int beg = n * CAP;
    const int end = beg + cnt[n];
    const float ad = a_dst[n];

    // pass 1: max
    float mx = -1e30f;
    for (int p = beg + lane; p < end; p += 64) {
        float v = a_src[csr_src[p]] + ad;
        v = v >= 0.f ? v : 0.2f * v;
        mx = fmaxf(mx, v);
    }
#pragma unroll
    for (int o = 32; o; o >>= 1) mx = fmaxf(mx, __shfl_xor(mx, o));

    // pass 2: 4-edge unroll, int4 index loads
    float ssum = 0.f;
    float a0 = 0.f, a1 = 0.f;
    int p = beg;
    for (; p + 3 < end; p += 4) {
        int4 s4 = *(const int4*)(csr_src + p);
        uint32_t u0 = *(const uint32_t*)(h2 + (size_t)s4.x * F2 + lane * 2);
        uint32_t u1 = *(const uint32_t*)(h2 + (size_t)s4.y * F2 + lane * 2);
        uint32_t u2 = *(const uint32_t*)(h2 + (size_t)s4.z * F2 + lane * 2);
        uint32_t u3 = *(const uint32_t*)(h2 + (size_t)s4.w * F2 + lane * 2);
        float c0 = expf(LREL(a_src[s4.x] + ad) - mx);
        float c1 = expf(LREL(a_src[s4.y] + ad) - mx);
        float c2 = expf(LREL(a_src[s4.z] + ad) - mx);
        float c3 = expf(LREL(a_src[s4.w] + ad) - mx);
        ssum += c0 + c1 + c2 + c3;
        a0 = fmaf(c0, bf_lo(u0), a0); a1 = fmaf(c0, bf_hi(u0), a1);
        a0 = fmaf(c1, bf_lo(u1), a0); a1 = fmaf(c1, bf_hi(u1), a1);
        a0 = fmaf(c2, bf_lo(u2), a0); a1 = fmaf(c2, bf_hi(u2), a1);
        a0 = fmaf(c3, bf_lo(u3), a0); a1 = fmaf(c3, bf_hi(u3), a1);
    }
    for (; p < end; p++) {
        int s0 = csr_src[p];
        uint32_t u0 = *(const uint32_t*)(h2 + (size_t)s0 * F2 + lane * 2);
        float c0 = expf(LREL(a_src[s0] + ad) - mx);
        ssum += c0;
        a0 = fmaf(c0, bf_lo(u0), a0); a1 = fmaf(c0, bf_hi(u0), a1);
    }
    const float inv = 1.0f / (ssum + 1e-16f);
    float v0 = fmaf(a0, inv, b2[lane * 2]);     v0 = v0 > 0.f ? v0 : 0.f;
    float v1 = fmaf(a1, inv, b2[lane * 2 + 1]); v1 = v1 > 0.f ? v1 : 0.f;
    float pr = v0 * outW[lane * 2] + v1 * outW[lane * 2 + 1];
    for (int o = 32; o; o >>= 1) pr += __shfl_xor(pr, o);
    if (lane == 0) out[n] = pr + outb[0];
}

// =======================================================================
extern "C" void kernel_launch(void* const* d_in, const int* in_sizes, int n_in,
                              void* d_out, int out_size, void* d_ws, size_t ws_size,
                              hipStream_t stream)
{
    const float* x        = (const float*)d_in[0];   // [NN, INCH]
    const float* cond     = (const float*)d_in[1];   // [NG, CONDCH]
    const float* W1       = (const float*)d_in[2];   // [INCH+CONDCH, F1]
    const float* att_src1 = (const float*)d_in[3];
    const float* att_dst1 = (const float*)d_in[4];
    const float* b1       = (const float*)d_in[5];
    const float* W2       = (const float*)d_in[6];   // [F1, F2]
    const float* att_src2 = (const float*)d_in[7];
    const float* att_dst2 = (const float*)d_in[8];
    const float* b2       = (const float*)d_in[9];
    const float* outW     = (const float*)d_in[10];
    const float* outb     = (const float*)d_in[11];
    const int*   ei       = (const int*)d_in[12];    // [2, NE]
    const int*   batch    = (const int*)d_in[13];    // [NN]
    float* out = (float*)d_out;

    // ---- workspace layout ----
    char* ws = (char*)d_ws;
    size_t off = 0;
    auto alloc = [&](size_t bytes) { void* p = ws + off; off += (bytes + 255) & ~size_t(255); return p; };
    ushort_t* xb      = (ushort_t*)alloc((size_t)MPAD * INCH * 2);    // 77.1 MB (aliased by g1b)
    ushort_t* condb   = (ushort_t*)alloc((size_t)NG * CONDCH * 2);
    ushort_t* W1aT    = (ushort_t*)alloc((size_t)F1 * INCH * 2);      // [512][768]
    ushort_t* W1cT    = (ushort_t*)alloc((size_t)F1 * CONDCH * 2);    // [512][768]
    ushort_t* W2T     = (ushort_t*)alloc((size_t)F2 * F1 * 2);        // [128][512]
    float*    C2      = (float*)alloc((size_t)NG * F1 * 4);           // [128][512]
    ushort_t* h1b     = (ushort_t*)alloc((size_t)NN * F1 * 2);        // 51.2 MB
    float*    a_src1  = (float*)alloc((size_t)NN * NHEAD * 4);
    float*    a_dst1  = (float*)alloc((size_t)NN * NHEAD * 4);
    int*      cursor  = (int*)alloc((size_t)NN * 4);
    int*      csr_src = (int*)alloc((size_t)NN * CAP * 4);            // 12.8 MB buckets
    ushort_t* h2b     = (ushort_t*)alloc((size_t)NN * F2 * 2);        // 12.8 MB
    float*    a_src2  = (float*)alloc((size_t)NN * 4);
    float*    a_dst2  = (float*)alloc((size_t)NN * 4);
    ushort_t* g1b     = xb;   // alias: xb dead after GEMM1; g1b written in agg1
    (void)ws_size;

    // ---- prep: cond cvt + weight transposes + bucket seed (cursor=1, self loop) ----
    k_prep<<<(R3 + 255) / 256, 256, 0, stream>>>(W1, W2, cond, W1aT, W1cT, W2T, condb,
                                                 cursor, csr_src);

    // ---- edge scatter ----
    k_scat<<<(NE + 255) / 256, 256, 0, stream>>>(ei, cursor, csr_src);

    // ---- x -> bf16: 32 elems/thread, 8 loads in flight (latency fix) ----
    {
        long n32 = (long)NN * INCH / 32;   // 1.2M threads
        k_cvt32<<<(int)((n32 + 255) / 256), 256, 0, stream>>>(x, xb, n32);
    }

    // ---- C2 = cond @ W1c  -> f32 [128][512] ----
    k_mgemm<128, false, false, false><<<4, 256, 0, stream>>>(
        condb, W1cT, C2, NG, F1, CONDCH, 4,
        nullptr, nullptr, nullptr, nullptr, nullptr, nullptr, 0);
    // ---- h1 = bf16( x @ W1a + C2[batch] ), fused att1 logits ----
    k_mgemm<256, true, true, true><<<(MPAD / 256) * 4, 512, 0, stream>>>(
        xb, W1aT, h1b, NN, F1, INCH, 4,
        C2, batch, att_src1, att_dst1, a_src1, a_dst1, NHEAD);
    // ---- aggregate layer1 (in-kernel softmax, +b1, relu) -> g1 bf16 ----
    k_agg1<<<NN / 4, 256, 0, stream>>>(h1b, a_src1, a_dst1, cursor, csr_src, b1, g1b);
    // ---- h2 = bf16( g1 @ W2 ), fused att2 logits ----
    k_mgemm<128, false, true, true><<<MPAD / 128, 256, 0, stream>>>(
        g1b, W2T, h2b, NN, F2, F1, 1,
        nullptr, nullptr, att_src2, att_dst2, a_src2, a_dst2, 1);
    // ---- aggregate layer2 (in-kernel softmax) + final linear -> out ----
    k_agg2<<<NN / 4, 256, 0, stream>>>(h2b, a_src2, a_dst2, cursor, csr_src, b2, outW, outb, out);
}

// Round 18
// 284.102 us; speedup vs baseline: 1.0109x; 1.0109x over previous
//
#include <hip/hip_runtime.h>
#include <hip/hip_bf16.h>
#include <cstdint>
#include <cstddef>

#define NN 50000        // nodes
#define NE 400000       // edges (without self loops)
#define NG 128
#define INCH 768
#define CONDCH 768
#define HIDD 128
#define NHEAD 4
#define F1 (NHEAD * HIDD)   // 512
#define F2 HIDD             // 128
#define MPAD 50176          // 784 * 64
#define CAP 64              // per-node edge bucket capacity (deg ~ Poisson(8))

typedef unsigned short ushort_t;
typedef float f32x4 __attribute__((ext_vector_type(4)));
typedef __bf16 bf16x8 __attribute__((ext_vector_type(8)));

typedef const void __attribute__((address_space(1))) as1_void;
typedef void __attribute__((address_space(3))) as3_void;

__device__ __forceinline__ void gload_lds16(const void* g, void* l) {
    __builtin_amdgcn_global_load_lds((as1_void*)g, (as3_void*)l, 16, 0, 0);
}

__device__ __forceinline__ ushort_t f2bf(float f) {
    uint32_t u = __float_as_uint(f);
    uint32_t r = (u + 0x7fffu + ((u >> 16) & 1u)) >> 16;
    return (ushort_t)r;
}
__device__ __forceinline__ uint32_t pack2(float a, float b) {
    return (uint32_t)f2bf(a) | ((uint32_t)f2bf(b) << 16);
}
__device__ __forceinline__ float bf_lo(uint32_t u) { return __uint_as_float(u << 16); }
__device__ __forceinline__ float bf_hi(uint32_t u) { return __uint_as_float(u & 0xffff0000u); }

// ---------------- k_prep: cond->bf16, weight transposes, bucket seed ------------
#define R1 (F1 * INCH)
#define R2 (R1 + F1 * CONDCH)
#define R3 (R2 + F2 * F1)
#define CND4 (NG * CONDCH / 4)
__global__ __launch_bounds__(256) void k_prep(
    const float* __restrict__ W1, const float* __restrict__ W2, const float* __restrict__ cond,
    ushort_t* __restrict__ W1aT, ushort_t* __restrict__ W1cT, ushort_t* __restrict__ W2T,
    ushort_t* __restrict__ condb, int* __restrict__ cursor, int* __restrict__ csr_src)
{
    int idx = blockIdx.x * blockDim.x + threadIdx.x;
    if (idx < NN) {
        cursor[idx] = 1;                       // self-loop pre-seeded
        csr_src[(size_t)idx * CAP] = idx;
    }
    if (idx < CND4) {
        float4 v = *(const float4*)(cond + (size_t)idx * 4);
        ushort4 o;
        o.x = f2bf(v.x); o.y = f2bf(v.y); o.z = f2bf(v.z); o.w = f2bf(v.w);
        *(ushort4*)(condb + (size_t)idx * 4) = o;
    }
    if (idx >= R3) return;
    if (idx < R1) {
        int n = idx / INCH, k = idx % INCH;
        W1aT[idx] = f2bf(W1[(size_t)k * F1 + n]);
    } else if (idx < R2) {
        int j = idx - R1;
        int n = j / CONDCH, k = j % CONDCH;
        W1cT[j] = f2bf(W1[(size_t)(INCH + k) * F1 + n]);
    } else {
        int j = idx - R2;
        int n = j / F1, k = j % F1;
        W2T[j] = f2bf(W2[(size_t)k * F2 + n]);
    }
}

// ---------------- edge scatter into buckets -----------------------
__global__ __launch_bounds__(256) void k_scat(const int* __restrict__ ei,
                                              int* __restrict__ cursor,
                                              int* __restrict__ csr_src) {
    int e = blockIdx.x * blockDim.x + threadIdx.x;
    if (e >= NE) return;
    int src = ei[e];
    int dst = ei[NE + e];
    int pos = atomicAdd(&cursor[dst], 1);
    csr_src[(size_t)dst * CAP + pos] = src;
}

// ================= GEMM1 wide: h1 = bf16( x @ W1aT^T + C2[batch] ), fused att ===
// Tile 64(M) x 512(full N); 8 waves = 1x8 columns, each wave 64x64.
// A staged RAW F32 from x via global_load_lds with chunk swizzle (R13-verified);
// B (W1aT, 768 KB total -> L2-resident) staged bf16. x read from HBM exactly once.
// 1 barrier per K-step: { vmcnt(0); s_barrier; STAGE(t+1->buf^1); compute buf }.
__global__ __launch_bounds__(512, 4) void k_gemm1w(
    const float* __restrict__ Af, const ushort_t* __restrict__ BT,
    ushort_t* __restrict__ Cv, const float* __restrict__ C2, const int* __restrict__ gidx,
    const float* __restrict__ attS, const float* __restrict__ attD,
    float* __restrict__ aS, float* __restrict__ aD)
{
    constexpr int SAB = 64 * 128;     // 8 KB per A buffer (64 rows x 128B f32)
    constexpr int SBB = 512 * 64;     // 32 KB per B buffer (512 n-rows x 64B bf16)
    __shared__ __align__(16) char smem[2 * SAB + 2 * SBB];   // 80 KB
    char* sA = smem;
    char* sB = smem + 2 * SAB;

    const int tid = threadIdx.x;
    const int lane = tid & 63;
    const int wave = tid >> 6;            // 0..7 -> column group wave*64; head = wave>>1
    const int m0 = blockIdx.x * 64;

    // A staging (f32): thread t -> row t>>3 (0..63), chunk (t&7)^(row&7) [swizzle]
    const int arow = tid >> 3;
    const int achunk = (tid & 7) ^ (arow & 7);
    int ar = m0 + arow; if (ar > NN - 1) ar = NN - 1;
    const float* gAf = Af + (size_t)ar * INCH + achunk * 4;

    // B staging (bf16): 4 issues; issue j covers n-rows [j*128, j*128+128)
    const int bro = tid >> 2;             // 0..127
    const int bco = (tid & 3) * 8;
    const ushort_t* gB0 = BT + (size_t)bro * INCH + bco;
    const int ldsw = wave * 1024;         // uniform base per issue

    // fragment read offsets
    const int b_off = (wave * 64 + (lane & 15)) * 64 + (lane >> 4) * 16;
    const int q32 = (lane >> 4) * 32;

    auto STAGE = [&](int kt, int b) {
        gload_lds16(gAf + kt, sA + b * SAB + ldsw);              // A: 1 issue (8 KB)
#pragma unroll
        for (int j = 0; j < 4; j++)                               // B: 4 issues (32 KB)
            gload_lds16(gB0 + (size_t)j * 128 * INCH + kt, sB + b * SBB + j * 8192 + ldsw);
    };

    f32x4 acc[4][4];
#pragma unroll
    for (int i = 0; i < 4; i++)
#pragma unroll
        for (int j = 0; j < 4; j++) acc[i][j] = 0.f;

    STAGE(0, 0);
    const int nt = INCH / 32;   // 24 (even)
    for (int t = 0; t < nt; t++) {
        const int cur = t & 1;
        asm volatile("s_waitcnt vmcnt(0)" ::: "memory");
        __builtin_amdgcn_s_barrier();
        __builtin_amdgcn_sched_barrier(0);
        if (t + 1 < nt) STAGE((t + 1) * 32, cur ^ 1);
        bf16x8 af[4], bfr[4];
#pragma unroll
        for (int i = 0; i < 4; i++) {
            int rw = i * 16 + (lane & 15);
            int sw = (rw & 7) << 4;
            const char* base = sA + cur * SAB + rw * 128;
            float4 lo = *(const float4*)(base + (q32 ^ sw));
            float4 hi = *(const float4*)(base + ((q32 + 16) ^ sw));
            bf16x8 v;
            v[0] = (__bf16)lo.x; v[1] = (__bf16)lo.y; v[2] = (__bf16)lo.z; v[3] = (__bf16)lo.w;
            v[4] = (__bf16)hi.x; v[5] = (__bf16)hi.y; v[6] = (__bf16)hi.z; v[7] = (__bf16)hi.w;
            af[i] = v;
        }
#pragma unroll
        for (int j = 0; j < 4; j++) bfr[j] = *(const bf16x8*)(sB + cur * SBB + b_off + j * 1024);
#pragma unroll
        for (int i = 0; i < 4; i++)
#pragma unroll
            for (int j = 0; j < 4; j++)
                acc[i][j] = __builtin_amdgcn_mfma_f32_16x16x32_bf16(af[i], bfr[j], acc[i][j], 0, 0, 0);
    }
    // nt even => last compute read buffer 1; epilogue reuses buffer-0 A region (8KB).

    // att vectors: column n global, flat att_src1/att_dst1 [512]
    float asv[4], adv[4];
#pragma unroll
    for (int j = 0; j < 4; j++) {
        int n = wave * 64 + j * 16 + (lane & 15);
        asv[j] = attS[n];
        adv[j] = attD[n];
    }
    float* redS = (float*)smem;            // [8 waves][64 rows]
    float* redD = (float*)smem + 512;

#pragma unroll
    for (int i = 0; i < 4; i++) {
#pragma unroll
        for (int rr = 0; rr < 4; rr++) {
            int mloc = i * 16 + (lane >> 4) * 4 + rr;
            int m = m0 + mloc;
            if (m >= NN) continue;
            const float* grow = C2 + (size_t)gidx[m] * F1;
            float vs = 0.f, vd = 0.f;
#pragma unroll
            for (int j = 0; j < 4; j++) {
                int n = wave * 64 + j * 16 + (lane & 15);
                float v = acc[i][j][rr] + grow[n];
                Cv[(size_t)m * F1 + n] = f2bf(v);
                vs = fmaf(v, asv[j], vs);
                vd = fmaf(v, adv[j], vd);
            }
#pragma unroll
            for (int o = 1; o < 16; o <<= 1) { vs += __shfl_xor(vs, o); vd += __shfl_xor(vd, o); }
            if ((lane & 15) == 0) {
                redS[wave * 64 + mloc] = vs;
                redD[wave * 64 + mloc] = vd;
            }
        }
    }
    __syncthreads();
    {
        int sd = tid >> 8;            // 0:S 1:D
        int rem = tid & 255;
        int h = rem >> 6;             // head 0..3
        int mloc = rem & 63;
        int m = m0 + mloc;
        if (m < NN) {
            const float* rb = sd ? redD : redS;
            float v = rb[(2 * h) * 64 + mloc] + rb[(2 * h + 1) * 64 + mloc];
            (sd ? aD : aS)[(size_t)m * NHEAD + h] = v;
        }
    }
}

// ---------------- bf16 MFMA GEMM (C2 + GEMM2): C[M,N] = A @ BT^T ----------------
// TM x 128 tile, dbuf LDS, 1 barrier/K-step. FUSE_ATT: stride-1 att (H=1).
template <int TM, bool OUT_BF16, bool FUSE_ATT>
__global__ __launch_bounds__(TM * 2) void k_mgemm(
    const ushort_t* __restrict__ A, const ushort_t* __restrict__ BT, void* __restrict__ Cv,
    int M, int N, int K, int nBN,
    const float* __restrict__ attS, const float* __restrict__ attD,
    float* __restrict__ aS, float* __restrict__ aD)
{
    constexpr int SA = TM * 64;
    constexpr int SB = 8192;
    __shared__ __align__(16) char smem[2 * SA + 2 * SB];
    char* sA = smem;
    char* sB = smem + 2 * SA;

    const int nwg = gridDim.x;
    const int orig = blockIdx.x;
    const int q = nwg >> 3, r = nwg & 7;
    const int xcd = orig & 7, sid = orig >> 3;
    const int wg = (xcd < r ? xcd * (q + 1) : r * (q + 1) + (xcd - r) * q) + sid;
    const int bx = wg / nBN, by = wg % nBN;

    const int tid = threadIdx.x;
    const int lane = tid & 63;
    const int wave = tid >> 6;
    const int wr = wave >> 1, wc = wave & 1;
    const int m0 = bx * TM, n0 = by * 128;

    const int sr = tid >> 2;
    const int sc = (tid & 3) * 8;
    const ushort_t* gA = A + (size_t)(m0 + sr) * K + sc;
    const ushort_t* gB = BT + (size_t)(n0 + sr) * K + sc;
    const int ldsw = wave * 1024;

    const int a_off = (wr * 64 + (lane & 15)) * 64 + (lane >> 4) * 16;
    const int b_off = (wc * 64 + (lane & 15)) * 64 + (lane >> 4) * 16;

    auto STAGE = [&](int kt, int b) {
        char* dA = sA + b * SA + ldsw;
        gload_lds16(gA + kt, dA);
        gload_lds16(gA + (size_t)(TM / 2) * K + kt, dA + SA / 2);
        char* dB = sB + b * SB + ldsw;
        gload_lds16(gB + kt, dB);
        if (TM == 128)
            gload_lds16(gB + (size_t)64 * K + kt, dB + 4096);
    };

    f32x4 acc[4][4];
#pragma unroll
    for (int i = 0; i < 4; i++)
#pragma unroll
        for (int j = 0; j < 4; j++) acc[i][j] = 0.f;

    STAGE(0, 0);
    const int nt = K / 32;
    for (int t = 0; t < nt; t++) {
        const int cur = t & 1;
        asm volatile("s_waitcnt vmcnt(0)" ::: "memory");
        __builtin_amdgcn_s_barrier();
        __builtin_amdgcn_sched_barrier(0);
        if (t + 1 < nt) STAGE((t + 1) * 32, cur ^ 1);
        bf16x8 af[4], bfr[4];
#pragma unroll
        for (int i = 0; i < 4; i++) af[i]  = *(const bf16x8*)(sA + cur * SA + a_off + i * 1024);
#pragma unroll
        for (int j = 0; j < 4; j++) bfr[j] = *(const bf16x8*)(sB + cur * SB + b_off + j * 1024);
#pragma unroll
        for (int i = 0; i < 4; i++)
#pragma unroll
            for (int j = 0; j < 4; j++)
                acc[i][j] = __builtin_amdgcn_mfma_f32_16x16x32_bf16(af[i], bfr[j], acc[i][j], 0, 0, 0);
    }

    float asv[4], adv[4];
    if (FUSE_ATT) {
#pragma unroll
        for (int j = 0; j < 4; j++) {
            int col = wc * 64 + j * 16 + (lane & 15);
            asv[j] = attS[by * 128 + col];
            adv[j] = attD[by * 128 + col];
        }
    }
    float* redS = (float*)smem;
    float* redD = (float*)smem + 2 * TM;

#pragma unroll
    for (int i = 0; i < 4; i++) {
        int mbase = m0 + wr * 64 + i * 16 + (lane >> 4) * 4;
#pragma unroll
        for (int rr = 0; rr < 4; rr++) {
            int m = mbase + rr;
            if (m >= M) continue;
            float vs = 0.f, vd = 0.f;
#pragma unroll
            for (int j = 0; j < 4; j++) {
                int n = n0 + wc * 64 + j * 16 + (lane & 15);
                float v = acc[i][j][rr];
                if (OUT_BF16) ((ushort_t*)Cv)[(size_t)m * N + n] = f2bf(v);
                else          ((float*)Cv)[(size_t)m * N + n] = v;
                if (FUSE_ATT) { vs = fmaf(v, asv[j], vs); vd = fmaf(v, adv[j], vd); }
            }
            if (FUSE_ATT) {
#pragma unroll
                for (int o = 1; o < 16; o <<= 1) { vs += __shfl_xor(vs, o); vd += __shfl_xor(vd, o); }
                if ((lane & 15) == 0) {
                    int mloc = wr * 64 + i * 16 + (lane >> 4) * 4 + rr;
                    redS[wc * TM + mloc] = vs;
                    redD[wc * TM + mloc] = vd;
                }
            }
        }
    }
    if (FUSE_ATT) {
        __syncthreads();
        int sd = tid >= TM ? 1 : 0, mloc = tid & (TM - 1);
        int m = m0 + mloc;
        if (m < M) {
            const float* rb = sd ? redD : redS;
            float v = rb[mloc] + rb[TM + mloc];
            (sd ? aD : aS)[m] = v;
        }
    }
}

// ---------------- aggregation layer1: one wave per node, in-kernel softmax ------
__global__ __launch_bounds__(256) void k_agg1(
    const ushort_t* __restrict__ h1, const float* __restrict__ a_src, const float* __restrict__ a_dst,
    const int* __restrict__ cnt, const int* __restrict__ csr_src,
    const float* __restrict__ b1, ushort_t* __restrict__ g1)
{
    const int n = blockIdx.x * 4 + (threadIdx.x >> 6);
    const int lane = threadIdx.x & 63;
    const int head = lane >> 4;
    const int beg = n * CAP;
    const int end = beg + cnt[n];
    const float4 ad = *(const float4*)(a_dst + (size_t)n * 4);

    float mx[4] = {-1e30f, -1e30f, -1e30f, -1e30f};
    for (int p = beg + lane; p < end; p += 64) {
        int src = csr_src[p];
        float4 as = *(const float4*)(a_src + (size_t)src * 4);
        float v;
        v = as.x + ad.x; v = v >= 0.f ? v : 0.2f * v; mx[0] = fmaxf(mx[0], v);
        v = as.y + ad.y; v = v >= 0.f ? v : 0.2f * v; mx[1] = fmaxf(mx[1], v);
        v = as.z + ad.z; v = v >= 0.f ? v : 0.2f * v; mx[2] = fmaxf(mx[2], v);
        v = as.w + ad.w; v = v >= 0.f ? v : 0.2f * v; mx[3] = fmaxf(mx[3], v);
    }
#pragma unroll
    for (int o = 32; o; o >>= 1) {
        mx[0] = fmaxf(mx[0], __shfl_xor(mx[0], o));
        mx[1] = fmaxf(mx[1], __shfl_xor(mx[1], o));
        mx[2] = fmaxf(mx[2], __shfl_xor(mx[2], o));
        mx[3] = fmaxf(mx[3], __shfl_xor(mx[3], o));
    }
    const float m   = (head & 1) ? ((head & 2) ? mx[3] : mx[1]) : ((head & 2) ? mx[2] : mx[0]);
    const float adh = (head & 1) ? ((head & 2) ? ad.w : ad.y)   : ((head & 2) ? ad.z : ad.x);

    float ssum = 0.f;
    float a[8] = {0.f, 0.f, 0.f, 0.f, 0.f, 0.f, 0.f, 0.f};
    int p = beg;
#define LREL(l) ((l) >= 0.f ? (l) : 0.2f * (l))
#define ACC8(c, u) \
        a[0] = fmaf(c, bf_lo(u.x), a[0]); a[1] = fmaf(c, bf_hi(u.x), a[1]); \
        a[2] = fmaf(c, bf_lo(u.y), a[2]); a[3] = fmaf(c, bf_hi(u.y), a[3]); \
        a[4] = fmaf(c, bf_lo(u.z), a[4]); a[5] = fmaf(c, bf_hi(u.z), a[5]); \
        a[6] = fmaf(c, bf_lo(u.w), a[6]); a[7] = fmaf(c, bf_hi(u.w), a[7]);
    for (; p + 3 < end; p += 4) {
        int4 s4 = *(const int4*)(csr_src + p);
        uint4 u0 = *(const uint4*)(h1 + (size_t)s4.x * F1 + lane * 8);
        uint4 u1 = *(const uint4*)(h1 + (size_t)s4.y * F1 + lane * 8);
        uint4 u2 = *(const uint4*)(h1 + (size_t)s4.z * F1 + lane * 8);
        uint4 u3 = *(const uint4*)(h1 + (size_t)s4.w * F1 + lane * 8);
        float c0 = expf(LREL(a_src[s4.x * 4 + head] + adh) - m);
        float c1 = expf(LREL(a_src[s4.y * 4 + head] + adh) - m);
        float c2 = expf(LREL(a_src[s4.z * 4 + head] + adh) - m);
        float c3 = expf(LREL(a_src[s4.w * 4 + head] + adh) - m);
        ssum += c0 + c1 + c2 + c3;
        ACC8(c0, u0) ACC8(c1, u1) ACC8(c2, u2) ACC8(c3, u3)
    }
    for (; p < end; p++) {
        int s0 = csr_src[p];
        uint4 u0 = *(const uint4*)(h1 + (size_t)s0 * F1 + lane * 8);
        float c0 = expf(LREL(a_src[s0 * 4 + head] + adh) - m);
        ssum += c0;
        ACC8(c0, u0)
    }
#undef ACC8
    const float inv = 1.0f / (ssum + 1e-16f);
    const int ch = lane * 8;
    float4 bA = *(const float4*)(b1 + ch);
    float4 bB = *(const float4*)(b1 + ch + 4);
    uint4 ov;
    ov.x = pack2(fmaxf(fmaf(a[0], inv, bA.x), 0.f), fmaxf(fmaf(a[1], inv, bA.y), 0.f));
    ov.y = pack2(fmaxf(fmaf(a[2], inv, bA.z), 0.f), fmaxf(fmaf(a[3], inv, bA.w), 0.f));
    ov.z = pack2(fmaxf(fmaf(a[4], inv, bB.x), 0.f), fmaxf(fmaf(a[5], inv, bB.y), 0.f));
    ov.w = pack2(fmaxf(fmaf(a[6], inv, bB.z), 0.f), fmaxf(fmaf(a[7], inv, bB.w), 0.f));
    *(uint4*)(g1 + (size_t)n * F1 + ch) = ov;
}

// ---------------- aggregation layer2 + final linear: one wave per node ------
__global__ __launch_bounds__(256) void k_agg2(
    const ushort_t* __restrict__ h2, const float* __restrict__ a_src, const float* __restrict__ a_dst,
    const int* __restrict__ cnt, const int* __restrict__ csr_src,
    const float* __restrict__ b2, const float* __restrict__ outW, const float* __restrict__ outb,
    float* __restrict__ out)
{
    const int n = blockIdx.x * 4 + (threadIdx.x >> 6);
    const int lane = threadIdx.x & 63;
    const int beg = n * CAP;
    const int end = beg + cnt[n];
    const float ad = a_dst[n];

    float mx = -1e30f;
    for (int p = beg + lane; p < end; p += 64) {
        float v = a_src[csr_src[p]] + ad;
        v = v >= 0.f ? v : 0.2f * v;
        mx = fmaxf(mx, v);
    }
#pragma unroll
    for (int o = 32; o; o >>= 1) mx = fmaxf(mx, __shfl_xor(mx, o));

    float ssum = 0.f;
    float a0 = 0.f, a1 = 0.f;
    int p = beg;
    for (; p + 3 < end; p += 4) {
        int4 s4 = *(const int4*)(csr_src + p);
        uint32_t u0 = *(const uint32_t*)(h2 + (size_t)s4.x * F2 + lane * 2);
        uint32_t u1 = *(const uint32_t*)(h2 + (size_t)s4.y * F2 + lane * 2);
        uint32_t u2 = *(const uint32_t*)(h2 + (size_t)s4.z * F2 + lane * 2);
        uint32_t u3 = *(const uint32_t*)(h2 + (size_t)s4.w * F2 + lane * 2);
        float c0 = expf(LREL(a_src[s4.x] + ad) - mx);
        float c1 = expf(LREL(a_src[s4.y] + ad) - mx);
        float c2 = expf(LREL(a_src[s4.z] + ad) - mx);
        float c3 = expf(LREL(a_src[s4.w] + ad) - mx);
        ssum += c0 + c1 + c2 + c3;
        a0 = fmaf(c0, bf_lo(u0), a0); a1 = fmaf(c0, bf_hi(u0), a1);
        a0 = fmaf(c1, bf_lo(u1), a0); a1 = fmaf(c1, bf_hi(u1), a1);
        a0 = fmaf(c2, bf_lo(u2), a0); a1 = fmaf(c2, bf_hi(u2), a1);
        a0 = fmaf(c3, bf_lo(u3), a0); a1 = fmaf(c3, bf_hi(u3), a1);
    }
    for (; p < end; p++) {
        int s0 = csr_src[p];
        uint32_t u0 = *(const uint32_t*)(h2 + (size_t)s0 * F2 + lane * 2);
        float c0 = expf(LREL(a_src[s0] + ad) - mx);
        ssum += c0;
        a0 = fmaf(c0, bf_lo(u0), a0); a1 = fmaf(c0, bf_hi(u0), a1);
    }
    const float inv = 1.0f / (ssum + 1e-16f);
    float v0 = fmaf(a0, inv, b2[lane * 2]);     v0 = v0 > 0.f ? v0 : 0.f;
    float v1 = fmaf(a1, inv, b2[lane * 2 + 1]); v1 = v1 > 0.f ? v1 : 0.f;
    float pr = v0 * outW[lane * 2] + v1 * outW[lane * 2 + 1];
    for (int o = 32; o; o >>= 1) pr += __shfl_xor(pr, o);
    if (lane == 0) out[n] = pr + outb[0];
}

// =======================================================================
extern "C" void kernel_launch(void* const* d_in, const int* in_sizes, int n_in,
                              void* d_out, int out_size, void* d_ws, size_t ws_size,
                              hipStream_t stream)
{
    const float* x        = (const float*)d_in[0];   // [NN, INCH]
    const float* cond     = (const float*)d_in[1];   // [NG, CONDCH]
    const float* W1       = (const float*)d_in[2];   // [INCH+CONDCH, F1]
    const float* att_src1 = (const float*)d_in[3];
    const float* att_dst1 = (const float*)d_in[4];
    const float* b1       = (const float*)d_in[5];
    const float* W2       = (const float*)d_in[6];   // [F1, F2]
    const float* att_src2 = (const float*)d_in[7];
    const float* att_dst2 = (const float*)d_in[8];
    const float* b2       = (const float*)d_in[9];
    const float* outW     = (const float*)d_in[10];
    const float* outb     = (const float*)d_in[11];
    const int*   ei       = (const int*)d_in[12];    // [2, NE]
    const int*   batch    = (const int*)d_in[13];    // [NN]
    float* out = (float*)d_out;

    // ---- workspace layout ----
    char* ws = (char*)d_ws;
    size_t off = 0;
    auto alloc = [&](size_t bytes) { void* p = ws + off; off += (bytes + 255) & ~size_t(255); return p; };
    ushort_t* condb   = (ushort_t*)alloc((size_t)NG * CONDCH * 2);
    ushort_t* W1aT    = (ushort_t*)alloc((size_t)F1 * INCH * 2);      // [512][768]
    ushort_t* W1cT    = (ushort_t*)alloc((size_t)F1 * CONDCH * 2);    // [512][768]
    ushort_t* W2T     = (ushort_t*)alloc((size_t)F2 * F1 * 2);        // [128][512]
    float*    C2      = (float*)alloc((size_t)NG * F1 * 4);           // [128][512]
    ushort_t* h1b     = (ushort_t*)alloc((size_t)NN * F1 * 2);        // 51.2 MB
    float*    a_src1  = (float*)alloc((size_t)NN * NHEAD * 4);
    float*    a_dst1  = (float*)alloc((size_t)NN * NHEAD * 4);
    int*      cursor  = (int*)alloc((size_t)NN * 4);
    int*      csr_src = (int*)alloc((size_t)NN * CAP * 4);            // 12.8 MB buckets
    ushort_t* g1b     = (ushort_t*)alloc((size_t)MPAD * F1 * 2);      // 51.4 MB
    ushort_t* h2b     = (ushort_t*)alloc((size_t)NN * F2 * 2);        // 12.8 MB
    float*    a_src2  = (float*)alloc((size_t)NN * 4);
    float*    a_dst2  = (float*)alloc((size_t)NN * 4);
    (void)ws_size;

    // ---- prep: cond cvt + weight transposes + bucket seed ----
    k_prep<<<(R3 + 255) / 256, 256, 0, stream>>>(W1, W2, cond, W1aT, W1cT, W2T, condb,
                                                 cursor, csr_src);

    // ---- edge scatter ----
    k_scat<<<(NE + 255) / 256, 256, 0, stream>>>(ei, cursor, csr_src);

    // ---- C2 = cond @ W1c  -> f32 [128][512]  (bf16 path) ----
    k_mgemm<128, false, false><<<4, 256, 0, stream>>>(
        condb, W1cT, C2, NG, F1, CONDCH, 4, nullptr, nullptr, nullptr, nullptr);

    // ---- h1 = bf16( x @ W1a + C2[batch] ), fused att1 logits; wide 64x512 tile,
    //      A raw f32 (x read from HBM exactly once), B L2-resident ----
    k_gemm1w<<<MPAD / 64, 512, 0, stream>>>(
        x, W1aT, h1b, C2, batch, att_src1, att_dst1, a_src1, a_dst1);

    // ---- aggregate layer1 (in-kernel softmax, +b1, relu) -> g1 bf16 ----
    k_agg1<<<NN / 4, 256, 0, stream>>>(h1b, a_src1, a_dst1, cursor, csr_src, b1, g1b);

    // ---- h2 = bf16( g1 @ W2 ), fused att2 logits ----
    k_mgemm<128, true, true><<<MPAD / 128, 256, 0, stream>>>(
        g1b, W2T, h2b, NN, F2, F1, 1, att_src2, att_dst2, a_src2, a_dst2);

    // ---- aggregate layer2 (in-kernel softmax) + final linear -> out ----
    k_agg2<<<NN / 4, 256, 0, stream>>>(h2b, a_src2, a_dst2, cursor, csr_src, b2, outW, outb, out);
}

// Round 19
// 278.685 us; speedup vs baseline: 1.0305x; 1.0194x over previous
//
#include <hip/hip_runtime.h>
#include <hip/hip_bf16.h>
#include <cstdint>
#include <cstddef>

#define NN 50000        // nodes
#define NE 400000       // edges (without self loops)
#define NG 128
#define INCH 768
#define CONDCH 768
#define HIDD 128
#define NHEAD 4
#define F1 (NHEAD * HIDD)   // 512
#define F2 HIDD             // 128
#define MPAD 50176          // 196 * 256
#define CAP 64              // per-node edge bucket capacity (deg ~ Poisson(8))

typedef unsigned short ushort_t;
typedef float f32x4 __attribute__((ext_vector_type(4)));
typedef __bf16 bf16x8 __attribute__((ext_vector_type(8)));

typedef const void __attribute__((address_space(1))) as1_void;
typedef void __attribute__((address_space(3))) as3_void;

__device__ __forceinline__ void gload_lds16(const void* g, void* l) {
    __builtin_amdgcn_global_load_lds((as1_void*)g, (as3_void*)l, 16, 0, 0);
}

__device__ __forceinline__ ushort_t f2bf(float f) {
    uint32_t u = __float_as_uint(f);
    uint32_t r = (u + 0x7fffu + ((u >> 16) & 1u)) >> 16;
    return (ushort_t)r;
}
__device__ __forceinline__ uint32_t pack2(float a, float b) {
    return (uint32_t)f2bf(a) | ((uint32_t)f2bf(b) << 16);
}
__device__ __forceinline__ float bf_lo(uint32_t u) { return __uint_as_float(u << 16); }
__device__ __forceinline__ float bf_hi(uint32_t u) { return __uint_as_float(u & 0xffff0000u); }

// ---------------- k_prep: cond->bf16, weight transposes, bucket seed ------------
#define R1 (F1 * INCH)
#define R2 (R1 + F1 * CONDCH)
#define R3 (R2 + F2 * F1)
#define CND4 (NG * CONDCH / 4)
__global__ __launch_bounds__(256) void k_prep(
    const float* __restrict__ W1, const float* __restrict__ W2, const float* __restrict__ cond,
    ushort_t* __restrict__ W1aT, ushort_t* __restrict__ W1cT, ushort_t* __restrict__ W2T,
    ushort_t* __restrict__ condb, int* __restrict__ cursor, int* __restrict__ csr_src)
{
    int idx = blockIdx.x * blockDim.x + threadIdx.x;
    if (idx < NN) {
        cursor[idx] = 1;                       // self-loop pre-seeded
        csr_src[(size_t)idx * CAP] = idx;
    }
    if (idx < CND4) {
        float4 v = *(const float4*)(cond + (size_t)idx * 4);
        ushort4 o;
        o.x = f2bf(v.x); o.y = f2bf(v.y); o.z = f2bf(v.z); o.w = f2bf(v.w);
        *(ushort4*)(condb + (size_t)idx * 4) = o;
    }
    if (idx >= R3) return;
    if (idx < R1) {
        int n = idx / INCH, k = idx % INCH;
        W1aT[idx] = f2bf(W1[(size_t)k * F1 + n]);
    } else if (idx < R2) {
        int j = idx - R1;
        int n = j / CONDCH, k = j % CONDCH;
        W1cT[j] = f2bf(W1[(size_t)(INCH + k) * F1 + n]);
    } else {
        int j = idx - R2;
        int n = j / F1, k = j % F1;
        W2T[j] = f2bf(W2[(size_t)k * F2 + n]);
    }
}

// ---------------- edge scatter into buckets -----------------------
__global__ __launch_bounds__(256) void k_scat(const int* __restrict__ ei,
                                              int* __restrict__ cursor,
                                              int* __restrict__ csr_src) {
    int e = blockIdx.x * blockDim.x + threadIdx.x;
    if (e >= NE) return;
    int src = ei[e];
    int dst = ei[NE + e];
    int pos = atomicAdd(&cursor[dst], 1);
    csr_src[(size_t)dst * CAP + pos] = src;
}

// ---------------- bf16 MFMA GEMM, optional raw-f32 A staging --------------------
// C[M,N] = A @ BT^T (+G[gidx[m],:]).  TM x 128 tile, double-buffered LDS,
// 1 barrier per K-step: { vmcnt(0); s_barrier; STAGE(t+1->buf^1); compute buf }.
// A_F32: A staged as raw f32 via global_load_lds, 4 issues x (TM/4 rows) each
// (each issue stages threads*16B = TM/4 rows of 128B), both-sides XOR chunk
// swizzle (source chunk = (t&7)^(rowInIss&7); read chunk ^= row&7), converted
// to bf16 in-register at fragment-read time. No conversion pass needed.
// 1-D grid, XCD-chunked bijective swizzle, n-fast ordering.
// FUSE_ATT: per-row dots with attS/attD -> aS/aD[m*attStride + by].
template <int TM, bool A_F32, bool ADD_GATHER, bool OUT_BF16, bool FUSE_ATT>
__global__ __launch_bounds__(TM * 2, 4) void k_mgemm(
    const ushort_t* __restrict__ A, const float* __restrict__ Af, int Arowmax,
    const ushort_t* __restrict__ BT, void* __restrict__ Cv,
    int M, int N, int K, int nBN,
    const float* __restrict__ G, const int* __restrict__ gidx,
    const float* __restrict__ attS, const float* __restrict__ attD,
    float* __restrict__ aS, float* __restrict__ aD, int attStride)
{
    constexpr int SAB = A_F32 ? TM * 128 : TM * 64;  // bytes per A buffer
    constexpr int SB = 8192;                          // bytes per B buffer
    constexpr int ISS_BYTES = TM * 32;                // f32: LDS bytes per issue
    __shared__ __align__(16) char smem[2 * SAB + 2 * SB];
    char* sA = smem;
    char* sB = smem + 2 * SAB;

    const int nwg = gridDim.x;
    const int orig = blockIdx.x;
    const int q = nwg >> 3, r = nwg & 7;
    const int xcd = orig & 7, sid = orig >> 3;
    const int wg = (xcd < r ? xcd * (q + 1) : r * (q + 1) + (xcd - r) * q) + sid;
    const int bx = wg / nBN, by = wg % nBN;

    const int tid = threadIdx.x;
    const int lane = tid & 63;
    const int wave = tid >> 6;
    const int wr = wave >> 1, wc = wave & 1;
    const int m0 = bx * TM, n0 = by * 128;

    // bf16 staging: thread t covers row t>>2, 16B chunk (t&3)*8 elems
    const int sr = tid >> 2;
    const int sc = (tid & 3) * 8;
    const ushort_t* gA = A_F32 ? nullptr : (A + (size_t)(m0 + sr) * K + sc);
    const ushort_t* gB = BT + (size_t)(n0 + sr) * K + sc;
    const int ldsw = wave * 1024;

    // f32 A staging: 4 issues, issue j covers rows [j*(TM/4), (j+1)*(TM/4));
    // thread t -> rowInIss = t>>3 (0..TM/4-1), source chunk pre-swizzled.
    const float* gAf_base[4];
    if constexpr (A_F32) {
        const int rowInIss = tid >> 3;                      // 0..TM/4-1
        const int chunkS = (tid & 7) ^ (rowInIss & 7);      // both-sides swizzle
#pragma unroll
        for (int j = 0; j < 4; j++) {
            int rr = m0 + j * (TM / 4) + rowInIss;
            if (rr > Arowmax) rr = Arowmax;
            gAf_base[j] = Af + (size_t)rr * K + chunkS * 4;
        }
    }

    const int a_off = (wr * 64 + (lane & 15)) * 64 + (lane >> 4) * 16;
    const int b_off = (wc * 64 + (lane & 15)) * 64 + (lane >> 4) * 16;

    auto STAGE = [&](int kt, int b) {
        if constexpr (A_F32) {
#pragma unroll
            for (int j = 0; j < 4; j++)
                gload_lds16(gAf_base[j] + kt, sA + b * SAB + j * ISS_BYTES + ldsw);
        } else {
            char* dA = sA + b * SAB + ldsw;
            gload_lds16(gA + kt, dA);
            gload_lds16(gA + (size_t)(TM / 2) * K + kt, dA + SAB / 2);
        }
        char* dB = sB + b * SB + ldsw;
        gload_lds16(gB + kt, dB);
        if (TM == 128)
            gload_lds16(gB + (size_t)64 * K + kt, dB + 4096);
    };

    f32x4 acc[4][4];
#pragma unroll
    for (int i = 0; i < 4; i++)
#pragma unroll
        for (int j = 0; j < 4; j++) acc[i][j] = 0.f;

    STAGE(0, 0);
    const int nt = K / 32;   // even for K in {768, 512}
    for (int t = 0; t < nt; t++) {
        const int cur = t & 1;
        asm volatile("s_waitcnt vmcnt(0)" ::: "memory");   // stage(t) landed
        __builtin_amdgcn_s_barrier();
        __builtin_amdgcn_sched_barrier(0);
        if (t + 1 < nt) STAGE((t + 1) * 32, cur ^ 1);      // in flight across compute
        bf16x8 af[4], bfr[4];
        if constexpr (A_F32) {
            const int q32 = (lane >> 4) * 32;
#pragma unroll
            for (int i = 0; i < 4; i++) {
                int rw = wr * 64 + i * 16 + (lane & 15);
                int sw = (rw & 7) << 4;
                const char* base = sA + cur * SAB + rw * 128;
                float4 lo = *(const float4*)(base + (q32 ^ sw));
                float4 hi = *(const float4*)(base + ((q32 + 16) ^ sw));
                bf16x8 v;
                v[0] = (__bf16)lo.x; v[1] = (__bf16)lo.y; v[2] = (__bf16)lo.z; v[3] = (__bf16)lo.w;
                v[4] = (__bf16)hi.x; v[5] = (__bf16)hi.y; v[6] = (__bf16)hi.z; v[7] = (__bf16)hi.w;
                af[i] = v;
            }
        } else {
#pragma unroll
            for (int i = 0; i < 4; i++) af[i] = *(const bf16x8*)(sA + cur * SAB + a_off + i * 1024);
        }
#pragma unroll
        for (int j = 0; j < 4; j++) bfr[j] = *(const bf16x8*)(sB + cur * SB + b_off + j * 1024);
#pragma unroll
        for (int i = 0; i < 4; i++)
#pragma unroll
            for (int j = 0; j < 4; j++)
                acc[i][j] = __builtin_amdgcn_mfma_f32_16x16x32_bf16(af[i], bfr[j], acc[i][j], 0, 0, 0);
    }
    // nt even => last compute read buffer 1; epilogue reuses buffer-0 region.

    float asv[4], adv[4];
    if (FUSE_ATT) {
#pragma unroll
        for (int j = 0; j < 4; j++) {
            int col = wc * 64 + j * 16 + (lane & 15);
            asv[j] = attS[by * 128 + col];
            adv[j] = attD[by * 128 + col];
        }
    }
    float* redS = (float*)smem;              // [2(wc)][TM]  (buffer-0 region)
    float* redD = (float*)smem + 2 * TM;

#pragma unroll
    for (int i = 0; i < 4; i++) {
        int mbase = m0 + wr * 64 + i * 16 + (lane >> 4) * 4;
#pragma unroll
        for (int rr = 0; rr < 4; rr++) {
            int m = mbase + rr;
            if (m >= M) continue;
            const float* grow = nullptr;
            if (ADD_GATHER) grow = G + (size_t)gidx[m] * N;
            float vs = 0.f, vd = 0.f;
#pragma unroll
            for (int j = 0; j < 4; j++) {
                int n = n0 + wc * 64 + j * 16 + (lane & 15);
                float v = acc[i][j][rr];
                if (ADD_GATHER) v += grow[n];
                if (OUT_BF16) ((ushort_t*)Cv)[(size_t)m * N + n] = f2bf(v);
                else          ((float*)Cv)[(size_t)m * N + n] = v;
                if (FUSE_ATT) { vs = fmaf(v, asv[j], vs); vd = fmaf(v, adv[j], vd); }
            }
            if (FUSE_ATT) {
#pragma unroll
                for (int o = 1; o < 16; o <<= 1) { vs += __shfl_xor(vs, o); vd += __shfl_xor(vd, o); }
                if ((lane & 15) == 0) {
                    int mloc = wr * 64 + i * 16 + (lane >> 4) * 4 + rr;
                    redS[wc * TM + mloc] = vs;
                    redD[wc * TM + mloc] = vd;
                }
            }
        }
    }
    if (FUSE_ATT) {
        __syncthreads();
        int sd = tid >= TM ? 1 : 0, mloc = tid & (TM - 1);
        int m = m0 + mloc;
        if (m < M) {
            const float* rb = sd ? redD : redS;
            float v = rb[mloc] + rb[TM + mloc];
            (sd ? aD : aS)[(size_t)m * attStride + by] = v;
        }
    }
}

// ---------------- aggregation layer1: one wave per node, in-kernel softmax ------
__global__ __launch_bounds__(256) void k_agg1(
    const ushort_t* __restrict__ h1, const float* __restrict__ a_src, const float* __restrict__ a_dst,
    const int* __restrict__ cnt, const int* __restrict__ csr_src,
    const float* __restrict__ b1, ushort_t* __restrict__ g1)
{
    const int n = blockIdx.x * 4 + (threadIdx.x >> 6);
    const int lane = threadIdx.x & 63;
    const int head = lane >> 4;
    const int beg = n * CAP;
    const int end = beg + cnt[n];
    const float4 ad = *(const float4*)(a_dst + (size_t)n * 4);

    // pass 1: per-head max (lanes parallel; deg<=CAP=64 -> single iteration)
    float mx[4] = {-1e30f, -1e30f, -1e30f, -1e30f};
    for (int p = beg + lane; p < end; p += 64) {
        int src = csr_src[p];
        float4 as = *(const float4*)(a_src + (size_t)src * 4);
        float v;
        v = as.x + ad.x; v = v >= 0.f ? v : 0.2f * v; mx[0] = fmaxf(mx[0], v);
        v = as.y + ad.y; v = v >= 0.f ? v : 0.2f * v; mx[1] = fmaxf(mx[1], v);
        v = as.z + ad.z; v = v >= 0.f ? v : 0.2f * v; mx[2] = fmaxf(mx[2], v);
        v = as.w + ad.w; v = v >= 0.f ? v : 0.2f * v; mx[3] = fmaxf(mx[3], v);
    }
#pragma unroll
    for (int o = 32; o; o >>= 1) {
        mx[0] = fmaxf(mx[0], __shfl_xor(mx[0], o));
        mx[1] = fmaxf(mx[1], __shfl_xor(mx[1], o));
        mx[2] = fmaxf(mx[2], __shfl_xor(mx[2], o));
        mx[3] = fmaxf(mx[3], __shfl_xor(mx[3], o));
    }
    const float m   = (head & 1) ? ((head & 2) ? mx[3] : mx[1]) : ((head & 2) ? mx[2] : mx[0]);
    const float adh = (head & 1) ? ((head & 2) ? ad.w : ad.y)   : ((head & 2) ? ad.z : ad.x);

    // pass 2: gather + exp + accumulate, 4-edge unroll, int4 index loads
    float ssum = 0.f;
    float a[8] = {0.f, 0.f, 0.f, 0.f, 0.f, 0.f, 0.f, 0.f};
    int p = beg;
#define LREL(l) ((l) >= 0.f ? (l) : 0.2f * (l))
#define ACC8(c, u) \
        a[0] = fmaf(c, bf_lo(u.x), a[0]); a[1] = fmaf(c, bf_hi(u.x), a[1]); \
        a[2] = fmaf(c, bf_lo(u.y), a[2]); a[3] = fmaf(c, bf_hi(u.y), a[3]); \
        a[4] = fmaf(c, bf_lo(u.z), a[4]); a[5] = fmaf(c, bf_hi(u.z), a[5]); \
        a[6] = fmaf(c, bf_lo(u.w), a[6]); a[7] = fmaf(c, bf_hi(u.w), a[7]);
    for (; p + 3 < end; p += 4) {
        int4 s4 = *(const int4*)(csr_src + p);   // bucket base 64-aligned -> p 4-aligned
        uint4 u0 = *(const uint4*)(h1 + (size_t)s4.x * F1 + lane * 8);
        uint4 u1 = *(const uint4*)(h1 + (size_t)s4.y * F1 + lane * 8);
        uint4 u2 = *(const uint4*)(h1 + (size_t)s4.z * F1 + lane * 8);
        uint4 u3 = *(const uint4*)(h1 + (size_t)s4.w * F1 + lane * 8);
        float c0 = expf(LREL(a_src[s4.x * 4 + head] + adh) - m);
        float c1 = expf(LREL(a_src[s4.y * 4 + head] + adh) - m);
        float c2 = expf(LREL(a_src[s4.z * 4 + head] + adh) - m);
        float c3 = expf(LREL(a_src[s4.w * 4 + head] + adh) - m);
        ssum += c0 + c1 + c2 + c3;
        ACC8(c0, u0) ACC8(c1, u1) ACC8(c2, u2) ACC8(c3, u3)
    }
    for (; p < end; p++) {
        int s0 = csr_src[p];
        uint4 u0 = *(const uint4*)(h1 + (size_t)s0 * F1 + lane * 8);
        float c0 = expf(LREL(a_src[s0 * 4 + head] + adh) - m);
        ssum += c0;
        ACC8(c0, u0)
    }
#undef ACC8
    const float inv = 1.0f / (ssum + 1e-16f);
    const int ch = lane * 8;
    float4 bA = *(const float4*)(b1 + ch);
    float4 bB = *(const float4*)(b1 + ch + 4);
    uint4 ov;
    ov.x = pack2(fmaxf(fmaf(a[0], inv, bA.x), 0.f), fmaxf(fmaf(a[1], inv, bA.y), 0.f));
    ov.y = pack2(fmaxf(fmaf(a[2], inv, bA.z), 0.f), fmaxf(fmaf(a[3], inv, bA.w), 0.f));
    ov.z = pack2(fmaxf(fmaf(a[4], inv, bB.x), 0.f), fmaxf(fmaf(a[5], inv, bB.y), 0.f));
    ov.w = pack2(fmaxf(fmaf(a[6], inv, bB.z), 0.f), fmaxf(fmaf(a[7], inv, bB.w), 0.f));
    *(uint4*)(g1 + (size_t)n * F1 + ch) = ov;
}

// ---------------- aggregation layer2 + final linear: one wave per node ------
__global__ __launch_bounds__(256) void k_agg2(
    const ushort_t* __restrict__ h2, const float* __restrict__ a_src, const float* __restrict__ a_dst,
    const int* __restrict__ cnt, const int* __restrict__ csr_src,
    const float* __restrict__ b2, const float* __restrict__ outW, const float* __restrict__ outb,
    float* __restrict__ out)
{
    const int n = blockIdx.x * 4 + (threadIdx.x >> 6);
    const int lane = threadIdx.x & 63;
    const int beg = n * CAP;
    const int end = beg + cnt[n];
    const float ad = a_dst[n];

    // pass 1: max
    float mx = -1e30f;
    for (int p = beg + lane; p < end; p += 64) {
        float v = a_src[csr_src[p]] + ad;
        v = v >= 0.f ? v : 0.2f * v;
        mx = fmaxf(mx, v);
    }
#pragma unroll
    for (int o = 32; o; o >>= 1) mx = fmaxf(mx, __shfl_xor(mx, o));

    // pass 2: 4-edge unroll, int4 index loads
    float ssum = 0.f;
    float a0 = 0.f, a1 = 0.f;
    int p = beg;
    for (; p + 3 < end; p += 4) {
        int4 s4 = *(const int4*)(csr_src + p);
        uint32_t u0 = *(const uint32_t*)(h2 + (size_t)s4.x * F2 + lane * 2);
        uint32_t u1 = *(const uint32_t*)(h2 + (size_t)s4.y * F2 + lane * 2);
        uint32_t u2 = *(const uint32_t*)(h2 + (size_t)s4.z * F2 + lane * 2);
        uint32_t u3 = *(const uint32_t*)(h2 + (size_t)s4.w * F2 + lane * 2);
        float c0 = expf(LREL(a_src[s4.x] + ad) - mx);
        float c1 = expf(LREL(a_src[s4.y] + ad) - mx);
        float c2 = expf(LREL(a_src[s4.z] + ad) - mx);
        float c3 = expf(LREL(a_src[s4.w] + ad) - mx);
        ssum += c0 + c1 + c2 + c3;
        a0 = fmaf(c0, bf_lo(u0), a0); a1 = fmaf(c0, bf_hi(u0), a1);
        a0 = fmaf(c1, bf_lo(u1), a0); a1 = fmaf(c1, bf_hi(u1), a1);
        a0 = fmaf(c2, bf_lo(u2), a0); a1 = fmaf(c2, bf_hi(u2), a1);
        a0 = fmaf(c3, bf_lo(u3), a0); a1 = fmaf(c3, bf_hi(u3), a1);
    }
    for (; p < end; p++) {
        int s0 = csr_src[p];
        uint32_t u0 = *(const uint32_t*)(h2 + (size_t)s0 * F2 + lane * 2);
        float c0 = expf(LREL(a_src[s0] + ad) - mx);
        ssum += c0;
        a0 = fmaf(c0, bf_lo(u0), a0); a1 = fmaf(c0, bf_hi(u0), a1);
    }
    const float inv = 1.0f / (ssum + 1e-16f);
    float v0 = fmaf(a0, inv, b2[lane * 2]);     v0 = v0 > 0.f ? v0 : 0.f;
    float v1 = fmaf(a1, inv, b2[lane * 2 + 1]); v1 = v1 > 0.f ? v1 : 0.f;
    float pr = v0 * outW[lane * 2] + v1 * outW[lane * 2 + 1];
    for (int o = 32; o; o >>= 1) pr += __shfl_xor(pr, o);
    if (lane == 0) out[n] = pr + outb[0];
}

// =======================================================================
extern "C" void kernel_launch(void* const* d_in, const int* in_sizes, int n_in,
                              void* d_out, int out_size, void* d_ws, size_t ws_size,
                              hipStream_t stream)
{
    const float* x        = (const float*)d_in[0];   // [NN, INCH]
    const float* cond     = (const float*)d_in[1];   // [NG, CONDCH]
    const float* W1       = (const float*)d_in[2];   // [INCH+CONDCH, F1]
    const float* att_src1 = (const float*)d_in[3];
    const float* att_dst1 = (const float*)d_in[4];
    const float* b1       = (const float*)d_in[5];
    const float* W2       = (const float*)d_in[6];   // [F1, F2]
    const float* att_src2 = (const float*)d_in[7];
    const float* att_dst2 = (const float*)d_in[8];
    const float* b2       = (const float*)d_in[9];
    const float* outW     = (const float*)d_in[10];
    const float* outb     = (const float*)d_in[11];
    const int*   ei       = (const int*)d_in[12];    // [2, NE]
    const int*   batch    = (const int*)d_in[13];    // [NN]
    float* out = (float*)d_out;

    // ---- workspace layout ----
    char* ws = (char*)d_ws;
    size_t off = 0;
    auto alloc = [&](size_t bytes) { void* p = ws + off; off += (bytes + 255) & ~size_t(255); return p; };
    ushort_t* condb   = (ushort_t*)alloc((size_t)NG * CONDCH * 2);
    ushort_t* W1aT    = (ushort_t*)alloc((size_t)F1 * INCH * 2);      // [512][768]
    ushort_t* W1cT    = (ushort_t*)alloc((size_t)F1 * CONDCH * 2);    // [512][768]
    ushort_t* W2T     = (ushort_t*)alloc((size_t)F2 * F1 * 2);        // [128][512]
    float*    C2      = (float*)alloc((size_t)NG * F1 * 4);           // [128][512]
    ushort_t* h1b     = (ushort_t*)alloc((size_t)NN * F1 * 2);        // 51.2 MB
    float*    a_src1  = (float*)alloc((size_t)NN * NHEAD * 4);
    float*    a_dst1  = (float*)alloc((size_t)NN * NHEAD * 4);
    int*      cursor  = (int*)alloc((size_t)NN * 4);
    int*      csr_src = (int*)alloc((size_t)NN * CAP * 4);            // 12.8 MB buckets
    ushort_t* g1b     = (ushort_t*)alloc((size_t)MPAD * F1 * 2);      // 51.4 MB
    ushort_t* h2b     = (ushort_t*)alloc((size_t)NN * F2 * 2);        // 12.8 MB
    float*    a_src2  = (float*)alloc((size_t)NN * 4);
    float*    a_dst2  = (float*)alloc((size_t)NN * 4);
    (void)ws_size;

    // ---- prep: cond cvt + weight transposes + bucket seed (cursor=1, self loop) ----
    k_prep<<<(R3 + 255) / 256, 256, 0, stream>>>(W1, W2, cond, W1aT, W1cT, W2T, condb,
                                                 cursor, csr_src);

    // ---- edge scatter ----
    k_scat<<<(NE + 255) / 256, 256, 0, stream>>>(ei, cursor, csr_src);

    // ---- C2 = cond @ W1c  -> f32 [128][512]  (proven bf16 path) ----
    k_mgemm<128, false, false, false, false><<<4, 256, 0, stream>>>(
        condb, nullptr, 0, W1cT, C2, NG, F1, CONDCH, 4,
        nullptr, nullptr, nullptr, nullptr, nullptr, nullptr, 0);
    // ---- h1 = bf16( x @ W1a + C2[batch] ), fused att1 logits; x staged raw f32 ----
    k_mgemm<256, true, true, true, true><<<(MPAD / 256) * 4, 512, 0, stream>>>(
        nullptr, x, NN - 1, W1aT, h1b, NN, F1, INCH, 4,
        C2, batch, att_src1, att_dst1, a_src1, a_dst1, NHEAD);
    // ---- aggregate layer1 (in-kernel softmax, +b1, relu) -> g1 bf16 ----
    k_agg1<<<NN / 4, 256, 0, stream>>>(h1b, a_src1, a_dst1, cursor, csr_src, b1, g1b);
    // ---- h2 = bf16( g1 @ W2 ), fused att2 logits ----
    k_mgemm<128, false, false, true, true><<<MPAD / 128, 256, 0, stream>>>(
        g1b, nullptr, 0, W2T, h2b, NN, F2, F1, 1,
        nullptr, nullptr, att_src2, att_dst2, a_src2, a_dst2, 1);
    // ---- aggregate layer2 (in-kernel softmax) + final linear -> out ----
    k_agg2<<<NN / 4, 256, 0, stream>>>(h2b, a_src2, a_dst2, cursor, csr_src, b2, outW, outb, out);
}